// Round 2
// baseline (3688.968 us; speedup 1.0000x reference)
//
#include <hip/hip_runtime.h>

#define NUM_FIELDS 40
#define NPAIRS     780
#define EMBED      64
#define BATCH      2048
#define BB         64   // batches per block

// One block per (pair p, 64-batch chunk). 256 threads = 4 waves.
// LDS: W[p] as float4[64][16] (f x e4), vi rows as float4[64][16] (b x e4),
// both XOR-swizzled on the e4 index with (row>>2)&7 so compute-phase
// ds_read_b128 spreads across all 8 16B bank slots.
__global__ __launch_bounds__(256, 4)
void bilinear_fp32(const float* __restrict__ emb,
                   const float* __restrict__ W,
                   float* __restrict__ out) {
    __shared__ float4 W4[64 * 16];
    __shared__ float4 V4[64 * 16];

    const int p    = blockIdx.y;
    const int bblk = blockIdx.x * BB;

    // pair index -> (fi, fj) per np.triu_indices(40, k=1), row-major
    int rem = p, fi = 0, cnt = NUM_FIELDS - 1;
    while (rem >= cnt) { rem -= cnt; --cnt; ++fi; }
    const int fj = fi + 1 + rem;

    const int t = threadIdx.x;

    // ---- stage W[p]: 64x64 f32 = 1024 float4 ----
    const float4* Wp = (const float4*)(W + (size_t)p * EMBED * EMBED);
    #pragma unroll
    for (int k = 0; k < 4; ++k) {
        int n  = t + 256 * k;
        int f  = n >> 4;
        int e4 = n & 15;
        W4[f * 16 + (e4 ^ ((f >> 2) & 7))] = Wp[n];
    }
    // ---- stage vi rows: emb[bblk+b][fi][:] ----
    #pragma unroll
    for (int k = 0; k < 4; ++k) {
        int n  = t + 256 * k;
        int b  = n >> 4;
        int e4 = n & 15;
        const float4* src =
            (const float4*)(emb + ((size_t)(bblk + b) * NUM_FIELDS + fi) * EMBED);
        V4[b * 16 + (e4 ^ ((b >> 2) & 7))] = src[e4];
    }
    __syncthreads();

    const int fq = t & 15;   // f-quad: this thread's f = 4*fq + j, j=0..3
    const int g  = t >> 4;   // b-quad: this thread's b = 4*g  + i, i=0..3

    float acc[4][4];
    #pragma unroll
    for (int i = 0; i < 4; ++i)
        #pragma unroll
        for (int j = 0; j < 4; ++j) acc[i][j] = 0.f;

    #pragma unroll
    for (int e4 = 0; e4 < 16; ++e4) {
        const int es_w = e4 ^ (fq & 7);
        const int es_v = e4 ^ (g & 7);
        float4 wv[4], vv[4];
        #pragma unroll
        for (int j = 0; j < 4; ++j) wv[j] = W4[(4 * fq + j) * 16 + es_w];
        #pragma unroll
        for (int i = 0; i < 4; ++i) vv[i] = V4[(4 * g + i) * 16 + es_v];
        #pragma unroll
        for (int i = 0; i < 4; ++i)
            #pragma unroll
            for (int j = 0; j < 4; ++j)
                acc[i][j] += vv[i].x * wv[j].x + vv[i].y * wv[j].y
                           + vv[i].z * wv[j].z + vv[i].w * wv[j].w;
    }

    // ---- epilogue: multiply by vj and store (float4 coalesced) ----
    #pragma unroll
    for (int i = 0; i < 4; ++i) {
        const int b = bblk + 4 * g + i;
        const float4* vjp =
            (const float4*)(emb + ((size_t)b * NUM_FIELDS + fj) * EMBED);
        float4 vj = vjp[fq];
        float4 o;
        o.x = acc[i][0] * vj.x;
        o.y = acc[i][1] * vj.y;
        o.z = acc[i][2] * vj.z;
        o.w = acc[i][3] * vj.w;
        float4* op = (float4*)(out + ((size_t)b * NPAIRS + p) * EMBED);
        op[fq] = o;
    }
}

extern "C" void kernel_launch(void* const* d_in, const int* in_sizes, int n_in,
                              void* d_out, int out_size, void* d_ws, size_t ws_size,
                              hipStream_t stream) {
    const float* emb = (const float*)d_in[0];
    const float* W   = (const float*)d_in[1];
    float*       out = (float*)d_out;

    dim3 grid(BATCH / BB, NPAIRS);
    hipLaunchKernelGGL(bilinear_fp32, grid, dim3(256), 0, stream, emb, W, out);
}

// Round 3
// 261.375 us; speedup vs baseline: 14.1137x; 14.1137x over previous
//
#include <hip/hip_runtime.h>

#define NUM_FIELDS 40
#define NPAIRS     780
#define EMBED      64
#define BATCH      2048
#define BB         64              // batches per block
#define PT         26              // pairs per block (780 = 26*30)
#define NBC        (BATCH/BB)      // 32 b-chunks
#define NPC        (NPAIRS/PT)     // 30 p-chunks
#define NBLK       (NBC*NPC)       // 960 blocks (960 % 8 == 0)

typedef __attribute__((ext_vector_type(8))) short bf16x8;
typedef __attribute__((ext_vector_type(4))) short short4v;
typedef __attribute__((ext_vector_type(4))) float f32x4;

// f32 -> bf16, round-to-nearest-even (inputs finite)
__device__ __forceinline__ short f2bf(float f) {
    unsigned u = __builtin_bit_cast(unsigned, f);
    u += 0x7FFFu + ((u >> 16) & 1u);
    return (short)(u >> 16);
}

// One block: 64 batches x 26 consecutive pairs. Loop over p with double-
// buffered bf16 LDS staging of W[p] (64f x 64e) and VI (64b x 64e).
// LDS rows hold 8 slots of 16B (bf16x8); slot = (e>>3) ^ (row&7) XOR-swizzle
// so fragment ds_read_b128 spreads across all 8 bank-quads (2-way max = free).
// Writes: out[b][p0:p0+PT][:] = 6.5 KB contiguous span per b.
__global__ __launch_bounds__(256, 4)
void bilinear_mfma(const float* __restrict__ emb,
                   const float* __restrict__ Wg,
                   float* __restrict__ out) {
    __shared__ __align__(16) short WbS[2][64][8][8];  // [buf][f][slot][elem]
    __shared__ __align__(16) short VIS[2][64][8][8];  // [buf][b][slot][elem]

    // XCD-contiguous bijective remap: xcd = bid%8 owns orig in [xcd*120, +120)
    // -> resident blocks per XCD span ~2 p-chunks -> W hot set ~0.8 MB in L2.
    const int bid  = blockIdx.x;
    const int orig = (bid & 7) * (NBLK / 8) + (bid >> 3);
    const int bc   = orig % NBC;        // b-chunk varies fastest within orig
    const int pc   = orig / NBC;
    const int bblk = bc * BB;
    const int p0   = pc * PT;

    const int t = threadIdx.x;

    // (fi, fj) for p0 per np.triu_indices(40, k=1)
    int fi = 0, rem = p0, cnt = NUM_FIELDS - 1;
    while (rem >= cnt) { rem -= cnt; --cnt; ++fi; }
    int fj = fi + 1 + rem;

    // ---- prologue: stage W(p0), VI(fi) into buf 0 ----
    {
        const float4* Wp = (const float4*)(Wg + (size_t)p0 * EMBED * EMBED);
        #pragma unroll
        for (int k = 0; k < 4; ++k) {
            int n = t + 256 * k;
            int row = n >> 4, e4 = n & 15;
            float4 wv = Wp[n];
            float4 vv = *(const float4*)(emb +
                          ((size_t)(bblk + row) * NUM_FIELDS + fi) * EMBED + e4 * 4);
            int o = e4 >> 1, half = e4 & 1;
            int slot = o ^ (row & 7);
            short4v cw, cv;
            cw.x = f2bf(wv.x); cw.y = f2bf(wv.y); cw.z = f2bf(wv.z); cw.w = f2bf(wv.w);
            cv.x = f2bf(vv.x); cv.y = f2bf(vv.y); cv.z = f2bf(vv.z); cv.w = f2bf(vv.w);
            *(short4v*)&WbS[0][row][slot][half * 4] = cw;
            *(short4v*)&VIS[0][row][slot][half * 4] = cv;
        }
    }
    __syncthreads();

    const int w   = t >> 6;    // wave id 0..3 -> owns C rows (b) [16w, 16w+16)
    const int l   = t & 63;
    const int l15 = l & 15;
    const int l4  = l >> 4;

    for (int pi = 0; pi < PT; ++pi) {
        const int cur = pi & 1, nxt = cur ^ 1;
        const int p   = p0 + pi;

        // next (fi, fj)
        int fi_n = fi, fj_n = fj + 1;
        if (fj_n == NUM_FIELDS) { fi_n = fi + 1; fj_n = fi_n + 1; }

        // ---- prefetch next W / VI tiles into registers (issue early) ----
        float4 Wpre[4], Vpre[4];
        const bool havenext = (pi + 1 < PT);
        if (havenext) {
            const float4* Wp = (const float4*)(Wg + (size_t)(p + 1) * EMBED * EMBED);
            #pragma unroll
            for (int k = 0; k < 4; ++k) {
                int n = t + 256 * k;
                int row = n >> 4, e4 = n & 15;
                Wpre[k] = Wp[n];
                Vpre[k] = *(const float4*)(emb +
                            ((size_t)(bblk + row) * NUM_FIELDS + fi_n) * EMBED + e4 * 4);
            }
        }

        // ---- A fragments (VI rows of this wave) ----
        bf16x8 afr[2];
        #pragma unroll
        for (int kk = 0; kk < 2; ++kk) {
            int row  = 16 * w + l15;
            int slot = (kk * 4 + l4) ^ (row & 7);
            afr[kk] = *(const bf16x8*)&VIS[cur][row][slot][0];
        }

        // ---- C = VI * W^T via 8 mfma (4 f-tiles x 2 k-steps) ----
        f32x4 acc[4];
        #pragma unroll
        for (int nt = 0; nt < 4; ++nt) {
            acc[nt].x = 0.f; acc[nt].y = 0.f; acc[nt].z = 0.f; acc[nt].w = 0.f;
            #pragma unroll
            for (int kk = 0; kk < 2; ++kk) {
                int row  = 16 * nt + l15;
                int slot = (kk * 4 + l4) ^ (row & 7);
                bf16x8 bfr = *(const bf16x8*)&WbS[cur][row][slot][0];
                acc[nt] = __builtin_amdgcn_mfma_f32_16x16x32_bf16(afr[kk], bfr, acc[nt], 0, 0, 0);
            }
        }

        // ---- epilogue: * vj (f32 direct from global) and store ----
        // C/D map (m89-verified): col = lane&15 -> f; row = (lane>>4)*4 + reg -> b
        #pragma unroll
        for (int r = 0; r < 4; ++r) {
            const int    blocal = 16 * w + 4 * l4 + r;
            const size_t bg     = (size_t)(bblk + blocal);
            const float* vjrow  = emb + (bg * NUM_FIELDS + fj) * EMBED;
            float*       orow   = out + (bg * NPAIRS + p) * EMBED;
            #pragma unroll
            for (int nt = 0; nt < 4; ++nt) {
                int f = nt * 16 + l15;
                orow[f] = acc[nt][r] * vjrow[f];
            }
        }

        // ---- convert + LDS-write prefetched tiles into nxt (write late) ----
        if (havenext) {
            #pragma unroll
            for (int k = 0; k < 4; ++k) {
                int n = t + 256 * k;
                int row = n >> 4, e4 = n & 15;
                int o = e4 >> 1, half = e4 & 1;
                int slot = o ^ (row & 7);
                short4v cw, cv;
                cw.x = f2bf(Wpre[k].x); cw.y = f2bf(Wpre[k].y);
                cw.z = f2bf(Wpre[k].z); cw.w = f2bf(Wpre[k].w);
                cv.x = f2bf(Vpre[k].x); cv.y = f2bf(Vpre[k].y);
                cv.z = f2bf(Vpre[k].z); cv.w = f2bf(Vpre[k].w);
                *(short4v*)&WbS[nxt][row][slot][half * 4] = cw;
                *(short4v*)&VIS[nxt][row][slot][half * 4] = cv;
            }
        }

        fi = fi_n; fj = fj_n;
        __syncthreads();
    }
}

extern "C" void kernel_launch(void* const* d_in, const int* in_sizes, int n_in,
                              void* d_out, int out_size, void* d_ws, size_t ws_size,
                              hipStream_t stream) {
    const float* emb = (const float*)d_in[0];
    const float* W   = (const float*)d_in[1];
    float*       out = (float*)d_out;

    hipLaunchKernelGGL(bilinear_mfma, dim3(NBLK), dim3(256), 0, stream, emb, W, out);
}

// Round 5
// 162.292 us; speedup vs baseline: 22.7304x; 1.6105x over previous
//
#include <hip/hip_runtime.h>

#define NUM_FIELDS 40
#define NPAIRS     780
#define EMBED      64
#define BATCH      2048
#define BB         64              // batches per block
#define PT         26              // pairs per block (780 = 26*30)
#define NBC        (BATCH/BB)      // 32 b-chunks
#define NPC        (NPAIRS/PT)     // 30 p-chunks
#define NBLK       (NBC*NPC)       // 960 blocks (960 % 8 == 0)

typedef __attribute__((ext_vector_type(8))) short bf16x8;
typedef __attribute__((ext_vector_type(4))) short short4v;
typedef __attribute__((ext_vector_type(4))) float f32x4;

// f32 -> bf16, round-to-nearest-even (inputs finite)
__device__ __forceinline__ short f2bf(float f) {
    unsigned u = __builtin_bit_cast(unsigned, f);
    u += 0x7FFFu + ((u >> 16) & 1u);
    return (short)(u >> 16);
}

// Block = 64 batches x 26 consecutive pairs, p-loop inside.
// A = W rows (f), B = VI rows (b)  =>  D: f = 16*nt + 4*l4 + r (contiguous
// per thread), b = 16*w + l15  =>  float4 vj loads + f32x4 NT stores.
// W double-buffered in LDS (reg-prefetch early, ds_write late); VI staged
// once per distinct fi. XOR slot-swizzle keeps ds_read_b128 conflict-free.
__global__ __launch_bounds__(256, 4)
void bilinear_mfma2(const float* __restrict__ emb,
                    const float* __restrict__ Wg,
                    float* __restrict__ out) {
    __shared__ __align__(16) short WbS[2][64][8][8];  // [buf][f][slot][elem]
    __shared__ __align__(16) short VIS[64][8][8];     // [b][slot][elem]

    // XCD-contiguous bijective remap (NBLK % 8 == 0)
    const int bid  = blockIdx.x;
    const int orig = (bid & 7) * (NBLK / 8) + (bid >> 3);
    const int bc   = orig % NBC;
    const int pc   = orig / NBC;
    const int bblk = bc * BB;
    const int p0   = pc * PT;

    const int t = threadIdx.x;

    // (fi, fj) for p0 per np.triu_indices(40, k=1)
    int fi = 0, rem = p0, cnt = NUM_FIELDS - 1;
    while (rem >= cnt) { rem -= cnt; --cnt; ++fi; }
    int fj = fi + 1 + rem;

    // ---- prologue: stage W(p0) -> WbS[0], VI(fi) -> VIS ----
    {
        const float4* Wp = (const float4*)(Wg + (size_t)p0 * EMBED * EMBED);
        #pragma unroll
        for (int k = 0; k < 4; ++k) {
            int n = t + 256 * k;
            int row = n >> 4, e4 = n & 15;
            float4 wv = Wp[n];
            float4 vv = *(const float4*)(emb +
                          ((size_t)(bblk + row) * NUM_FIELDS + fi) * EMBED + e4 * 4);
            int o = e4 >> 1, half = e4 & 1;
            int slot = o ^ (row & 7);
            short4v cw, cv;
            cw.x = f2bf(wv.x); cw.y = f2bf(wv.y); cw.z = f2bf(wv.z); cw.w = f2bf(wv.w);
            cv.x = f2bf(vv.x); cv.y = f2bf(vv.y); cv.z = f2bf(vv.z); cv.w = f2bf(vv.w);
            *(short4v*)&WbS[0][row][slot][half * 4] = cw;
            *(short4v*)&VIS[row][slot][half * 4] = cv;
        }
    }
    __syncthreads();

    const int w   = t >> 6;    // wave id -> b-tile: b = 16*w + l15
    const int l   = t & 63;
    const int l15 = l & 15;
    const int l4  = l >> 4;

    const size_t bg    = (size_t)(bblk + 16 * w + l15);
    const float* vjbase = emb + bg * NUM_FIELDS * EMBED;
    float*       obase  = out + (bg * NPAIRS) * (size_t)EMBED;

    for (int pi = 0; pi < PT; ++pi) {
        const int cur = pi & 1, nxt = cur ^ 1;
        const int p   = p0 + pi;

        int fi_n = fi, fj_n = fj + 1;
        if (fj_n == NUM_FIELDS) { fi_n = fi + 1; fj_n = fi_n + 1; }

        const bool havenext  = (pi + 1 < PT);
        const bool fi_change = havenext && (fi_n != fi);

        // ---- issue next-tile global loads early ----
        float4 Wpre[4], Vpre[4];
        if (havenext) {
            const float4* Wp = (const float4*)(Wg + (size_t)(p + 1) * EMBED * EMBED);
            #pragma unroll
            for (int k = 0; k < 4; ++k) {
                int n = t + 256 * k;
                Wpre[k] = Wp[n];
            }
        }
        if (fi_change) {
            #pragma unroll
            for (int k = 0; k < 4; ++k) {
                int n = t + 256 * k;
                int row = n >> 4, e4 = n & 15;
                Vpre[k] = *(const float4*)(emb +
                            ((size_t)(bblk + row) * NUM_FIELDS + fi_n) * EMBED + e4 * 4);
            }
        }

        // ---- vj early (float4; b fixed per thread) ----
        const float* vjrow = vjbase + (size_t)fj * EMBED;
        float4 vj4[4];
        #pragma unroll
        for (int nt = 0; nt < 4; ++nt)
            vj4[nt] = *(const float4*)(vjrow + nt * 16 + l4 * 4);

        // ---- B fragments (VI rows of this wave) ----
        bf16x8 bfr[2];
        #pragma unroll
        for (int kk = 0; kk < 2; ++kk) {
            int row  = 16 * w + l15;
            int slot = (kk * 4 + l4) ^ (row & 7);
            bfr[kk] = *(const bf16x8*)&VIS[row][slot][0];
        }

        // ---- C[f][b] = W * VI^T : A = W rows, B = VI rows ----
        f32x4 acc[4];
        #pragma unroll
        for (int nt = 0; nt < 4; ++nt) {
            acc[nt].x = 0.f; acc[nt].y = 0.f; acc[nt].z = 0.f; acc[nt].w = 0.f;
            #pragma unroll
            for (int kk = 0; kk < 2; ++kk) {
                int row  = 16 * nt + l15;
                int slot = (kk * 4 + l4) ^ (row & 7);
                bf16x8 afr = *(const bf16x8*)&WbS[cur][row][slot][0];
                acc[nt] = __builtin_amdgcn_mfma_f32_16x16x32_bf16(afr, bfr[kk], acc[nt], 0, 0, 0);
            }
        }

        // ---- epilogue: o = acc * vj, nontemporal f32x4 store ----
        float* orow = obase + (size_t)p * EMBED;
        #pragma unroll
        for (int nt = 0; nt < 4; ++nt) {
            f32x4 o;
            o.x = acc[nt].x * vj4[nt].x;
            o.y = acc[nt].y * vj4[nt].y;
            o.z = acc[nt].z * vj4[nt].z;
            o.w = acc[nt].w * vj4[nt].w;
            __builtin_nontemporal_store(o, (f32x4*)(orow + nt * 16 + l4 * 4));
        }

        // ---- W ds_write into nxt buffer (no barrier needed before) ----
        if (havenext) {
            #pragma unroll
            for (int k = 0; k < 4; ++k) {
                int n = t + 256 * k;
                int row = n >> 4, e4 = n & 15;
                int o = e4 >> 1, half = e4 & 1;
                int slot = o ^ (row & 7);
                short4v cw;
                cw.x = f2bf(Wpre[k].x); cw.y = f2bf(Wpre[k].y);
                cw.z = f2bf(Wpre[k].z); cw.w = f2bf(Wpre[k].w);
                *(short4v*)&WbS[nxt][row][slot][half * 4] = cw;
            }
        }
        // ---- VI restage only when fi changes (extra barrier: rare) ----
        if (fi_change) {
            __syncthreads();   // all waves done reading VIS for this iter
            #pragma unroll
            for (int k = 0; k < 4; ++k) {
                int n = t + 256 * k;
                int row = n >> 4, e4 = n & 15;
                int o = e4 >> 1, half = e4 & 1;
                int slot = o ^ (row & 7);
                short4v cv;
                cv.x = f2bf(Vpre[k].x); cv.y = f2bf(Vpre[k].y);
                cv.z = f2bf(Vpre[k].z); cv.w = f2bf(Vpre[k].w);
                *(short4v*)&VIS[row][slot][half * 4] = cv;
            }
        }

        fi = fi_n; fj = fj_n;
        __syncthreads();
    }
}

extern "C" void kernel_launch(void* const* d_in, const int* in_sizes, int n_in,
                              void* d_out, int out_size, void* d_ws, size_t ws_size,
                              hipStream_t stream) {
    const float* emb = (const float*)d_in[0];
    const float* W   = (const float*)d_in[1];
    float*       out = (float*)d_out;

    hipLaunchKernelGGL(bilinear_mfma2, dim3(NBLK), dim3(256), 0, stream, emb, W, out);
}